// Round 18
// baseline (562.378 us; speedup 1.0000x reference)
//
#include <hip/hip_runtime.h>
#include <hip/hip_bf16.h>

// Problem constants
#define B_ 2
#define S_ 2048
#define H_ 16
#define HD_ 64
#define D_ 1024
#define NJ_ 257      // 2*MAX_REL+1
#define RSTRIDE_ 264 // padded row stride for R (16B aligned)

typedef __bf16 v8bf __attribute__((ext_vector_type(8)));
typedef __bf16 v4bf __attribute__((ext_vector_type(4)));
typedef float  v4f  __attribute__((ext_vector_type(4)));

static __device__ __forceinline__ v4f mfma16(v8bf a, v8bf b, v4f c) {
    return __builtin_amdgcn_mfma_f32_16x16x32_bf16(a, b, c, 0, 0, 0);
}

// ---------------------------------------------------------------------------
// Fused prep: x -> hi/lo split, rel -> hi/lo split, 4 weights -> bf16 cast
// ---------------------------------------------------------------------------
__global__ void k_prep(const float* __restrict__ x, const float* __restrict__ rel,
                       const float* __restrict__ wq, const float* __restrict__ wk,
                       const float* __restrict__ wv, const float* __restrict__ wo,
                       __bf16* __restrict__ xh, __bf16* __restrict__ xl,
                       __bf16* __restrict__ relh, __bf16* __restrict__ rell,
                       __bf16* __restrict__ wqh, __bf16* __restrict__ wkh,
                       __bf16* __restrict__ wvh, __bf16* __restrict__ woh) {
    const int NX = 1048576;
    const int NR = 4112;
    const int NW = 262144;
    const int total = NX + NR + 4 * NW;
    int i = blockIdx.x * blockDim.x + threadIdx.x;
    const int stride = gridDim.x * blockDim.x;
    for (; i < total; i += stride) {
        if (i < NX + NR) {
            const bool isx = i < NX;
            const int j = isx ? i : i - NX;
            const float* src = isx ? x : rel;
            __bf16* dh = isx ? xh : relh;
            __bf16* dl = isx ? xl : rell;
            const float4 v = ((const float4*)src)[j];
            float vv[4] = {v.x, v.y, v.z, v.w};
            v4bf hv, lv;
#pragma unroll
            for (int e = 0; e < 4; e++) {
                __bf16 hb = (__bf16)vv[e];
                hv[e] = hb;
                lv[e] = (__bf16)(vv[e] - (float)hb);
            }
            *(v4bf*)(dh + 4 * (size_t)j) = hv;
            *(v4bf*)(dl + 4 * (size_t)j) = lv;
        } else {
            const int j = i - NX - NR;
            const int region = j >> 18, idx = j & (NW - 1);
            const float* src = region == 0 ? wq : region == 1 ? wk : region == 2 ? wv : wo;
            __bf16* dst = region == 0 ? wqh : region == 1 ? wkh : region == 2 ? wvh : woh;
            const float4 v = ((const float4*)src)[idx];
            v4bf o = {(__bf16)v.x, (__bf16)v.y, (__bf16)v.z, (__bf16)v.w};
            *(v4bf*)(dst + 4 * (size_t)idx) = o;
        }
    }
}

// ---------------------------------------------------------------------------
// Per-(b,q) row flag: 1 if whole mask row is nonzero
// ---------------------------------------------------------------------------
__global__ void k_rowflag(const int* __restrict__ mask, unsigned char* __restrict__ flags) {
    const int row = blockIdx.x;
    const int4* mp = (const int4*)(mask + (size_t)row * S_);
    int ok = 1;
    for (int i = threadIdx.x; i < S_ / 4; i += blockDim.x) {
        int4 m = mp[i];
        ok &= (m.x != 0) & (m.y != 0) & (m.z != 0) & (m.w != 0);
    }
    int all = __syncthreads_and(ok);
    if (threadIdx.x == 0) flags[row] = (unsigned char)(all != 0);
}

// ---------------------------------------------------------------------------
// Fused QKV projection (LDS stride 76). seg 0: Q hi/lo; seg 1: K hi;
// seg 2: V -> written TRANSPOSED directly to Vt (fused vtrans).
// ---------------------------------------------------------------------------
__global__ __launch_bounds__(256) void k_projQKV(const __bf16* __restrict__ xh,
                                                 const __bf16* __restrict__ xl,
                                                 const __bf16* __restrict__ wqh,
                                                 const __bf16* __restrict__ wkh,
                                                 const __bf16* __restrict__ wvh,
                                                 __bf16* __restrict__ Qh,
                                                 __bf16* __restrict__ Ql,
                                                 __bf16* __restrict__ Kh,
                                                 __bf16* __restrict__ Vt) {
    __shared__ __bf16 sXh[64][76], sXl[64][76], sW[64][76];
    const int seg = blockIdx.x >> 4;
    const int n0 = (blockIdx.x & 15) * 64;
    const int m0 = blockIdx.y * 64;
    const __bf16* W = seg == 0 ? wqh : (seg == 1 ? wkh : wvh);
    const int tid = threadIdx.x, lane = tid & 63, wid = tid >> 6;
    const int fr = lane & 15, fo = (lane >> 4) * 8;
    const int srow = tid >> 2, scol = (tid & 3) * 16;
    v4f acc[4] = {};
    for (int k0 = 0; k0 < D_; k0 += 64) {
        const size_t ga = (size_t)(m0 + srow) * D_ + k0 + scol;
        const size_t gb = (size_t)(n0 + srow) * D_ + k0 + scol;
        *(v8bf*)&sXh[srow][scol]     = *(const v8bf*)(xh + ga);
        *(v8bf*)&sXh[srow][scol + 8] = *(const v8bf*)(xh + ga + 8);
        if (seg < 2) {
            *(v8bf*)&sXl[srow][scol]     = *(const v8bf*)(xl + ga);
            *(v8bf*)&sXl[srow][scol + 8] = *(const v8bf*)(xl + ga + 8);
        }
        *(v8bf*)&sW[srow][scol]     = *(const v8bf*)(W + gb);
        *(v8bf*)&sW[srow][scol + 8] = *(const v8bf*)(W + gb + 8);
        __syncthreads();
#pragma unroll
        for (int ks = 0; ks < 2; ks++) {
            v8bf ah = *(const v8bf*)&sXh[wid * 16 + fr][ks * 32 + fo];
            v8bf al;
            if (seg < 2) al = *(const v8bf*)&sXl[wid * 16 + fr][ks * 32 + fo];
#pragma unroll
            for (int nt = 0; nt < 4; nt++) {
                v8bf bb = *(const v8bf*)&sW[nt * 16 + fr][ks * 32 + fo];
                acc[nt] = mfma16(ah, bb, acc[nt]);
                if (seg < 2) acc[nt] = mfma16(al, bb, acc[nt]);
            }
        }
        __syncthreads();
    }
    if (seg == 2) {
#pragma unroll
        for (int nt = 0; nt < 4; nt++)
#pragma unroll
            for (int r = 0; r < 4; r++)
                sXh[wid * 16 + (lane >> 4) * 4 + r][nt * 16 + fr] = (__bf16)acc[nt][r];
        __syncthreads();
        const int c = tid >> 2;
        const int r0 = (tid & 3) * 16;
        v8bf o0, o1;
#pragma unroll
        for (int j = 0; j < 8; j++) {
            o0[j] = sXh[r0 + j][c];
            o1[j] = sXh[r0 + 8 + j][c];
        }
        const int b2 = m0 >> 11;
        const size_t gout = ((size_t)(b2 * D_ + n0 + c)) * S_ + (m0 & 2047) + r0;
        *(v8bf*)(Vt + gout)     = o0;
        *(v8bf*)(Vt + gout + 8) = o1;
    } else {
#pragma unroll
        for (int nt = 0; nt < 4; nt++) {
#pragma unroll
            for (int r = 0; r < 4; r++) {
                const int row = m0 + wid * 16 + (lane >> 4) * 4 + r;
                const int col = n0 + nt * 16 + fr;
                const size_t idx = (size_t)row * D_ + col;
                const float f = acc[nt][r];
                if (seg == 0) {
                    __bf16 hb = (__bf16)f;
                    Qh[idx] = hb;
                    Ql[idx] = (__bf16)(f - (float)hb);
                } else {
                    Kh[idx] = (__bf16)f;
                }
            }
        }
    }
}

// ---------------------------------------------------------------------------
// Rel-bias GEMM + per-row qnorm + per-row Rmax
// ---------------------------------------------------------------------------
__global__ __launch_bounds__(256) void k_relgemm(const __bf16* __restrict__ Qh,
                                                 const __bf16* __restrict__ Ql,
                                                 const __bf16* __restrict__ relh,
                                                 const __bf16* __restrict__ rell,
                                                 float* __restrict__ Rg,
                                                 float* __restrict__ qnorm,
                                                 float* __restrict__ Rmax) {
    const int q0 = blockIdx.x * 64;
    const int bh = blockIdx.y;
    const int b = bh >> 4, h = bh & 15;
    const int tid = threadIdx.x, lane = tid & 63, wid = tid >> 6;
    const int fr = lane & 15, fo = (lane >> 4) * 8;
    const size_t qbase = (size_t)(b * S_ + q0 + wid * 16 + fr) * D_ + h * HD_;
    v8bf qa_h[2], qa_l[2];
#pragma unroll
    for (int ks = 0; ks < 2; ks++) {
        qa_h[ks] = *(const v8bf*)(Qh + qbase + ks * 32 + fo);
        qa_l[ks] = *(const v8bf*)(Ql + qbase + ks * 32 + fo);
    }

    float qs = 0.0f;
#pragma unroll
    for (int ks = 0; ks < 2; ks++)
#pragma unroll
        for (int j = 0; j < 8; j++) {
            const float v = (float)qa_h[ks][j] + (float)qa_l[ks][j];
            qs += v * v;
        }
    qs += __shfl_xor(qs, 16);
    qs += __shfl_xor(qs, 32);
    if ((lane >> 4) == 0) qnorm[(size_t)bh * S_ + q0 + wid * 16 + fr] = sqrtf(qs);

    v4f acc[17] = {};
#pragma unroll
    for (int jt = 0; jt < 17; jt++) {
        int j = jt * 16 + fr;
        if (j > 256) j = 256;
        const size_t rb = (size_t)j * HD_;
#pragma unroll
        for (int ks = 0; ks < 2; ks++) {
            v8bf bh_ = *(const v8bf*)(relh + rb + ks * 32 + fo);
            v8bf bl_ = *(const v8bf*)(rell + rb + ks * 32 + fo);
            acc[jt] = mfma16(qa_h[ks], bh_, acc[jt]);
            acc[jt] = mfma16(qa_h[ks], bl_, acc[jt]);
            acc[jt] = mfma16(qa_l[ks], bh_, acc[jt]);
        }
    }

    float rm[4] = {-3.0e38f, -3.0e38f, -3.0e38f, -3.0e38f};
#pragma unroll
    for (int jt = 0; jt < 17; jt++)
#pragma unroll
        for (int r = 0; r < 4; r++) rm[r] = fmaxf(rm[r], acc[jt][r]);
#pragma unroll
    for (int r = 0; r < 4; r++) {
#pragma unroll
        for (int sh = 1; sh < 16; sh <<= 1) rm[r] = fmaxf(rm[r], __shfl_xor(rm[r], sh));
    }
    if (fr == 0) {
#pragma unroll
        for (int r = 0; r < 4; r++)
            Rmax[(size_t)bh * S_ + q0 + wid * 16 + (lane >> 4) * 4 + r] = rm[r];
    }

    const size_t rowbase = ((size_t)bh * S_ + q0 + wid * 16 + (lane >> 4) * 4) * RSTRIDE_;
#pragma unroll
    for (int jt = 0; jt < 17; jt++) {
        const int j = jt * 16 + fr;
        if (j <= 256) {
#pragma unroll
            for (int r = 0; r < 4; r++)
                Rg[rowbase + (size_t)r * RSTRIDE_ + j] = acc[jt][r];
        }
    }
}

// ---------------------------------------------------------------------------
// Kmax per (b,h): max over k of ||Kh[b,k,h*64..]||
// ---------------------------------------------------------------------------
__global__ __launch_bounds__(256) void k_knorm(const __bf16* __restrict__ Kh,
                                               float* __restrict__ Kmax) {
    __shared__ float red[4];
    const int bh = blockIdx.x, b = bh >> 4, h = bh & 15;
    const int tid = threadIdx.x;
    float best = 0.0f;
#pragma unroll
    for (int i = 0; i < 8; i++) {
        const int k = tid + i * 256;
        const __bf16* kr = Kh + (size_t)(b * S_ + k) * D_ + h * HD_;
        float s = 0.0f;
#pragma unroll
        for (int j = 0; j < 8; j++) {
            v8bf v = *(const v8bf*)(kr + j * 8);
#pragma unroll
            for (int e = 0; e < 8; e++) { const float f = (float)v[e]; s += f * f; }
        }
        best = fmaxf(best, s);
    }
#pragma unroll
    for (int sh = 1; sh < 64; sh <<= 1) best = fmaxf(best, __shfl_xor(best, sh));
    if ((tid & 63) == 0) red[tid >> 6] = best;
    __syncthreads();
    if (tid == 0)
        Kmax[bh] = sqrtf(fmaxf(fmaxf(red[0], red[1]), fmaxf(red[2], red[3])));
}

// ---------------------------------------------------------------------------
// Single-pass attention, 1024 threads (16 waves = 8 row-groups x 2 col-halves):
//   same 128-row q-tile / traffic pattern as R12; wc-split halves per-wave
//   registers so 2 blocks/CU = 8 waves/SIMD (2x TLP for BW). Dbuf K/V,
//   stride-76 LDS, 2 counted (lgkmcnt-only) barriers/chunk, full-128B-line
//   E writes (row-assigned post-barrier), fused rescale epilogue.
// ---------------------------------------------------------------------------
__global__ __launch_bounds__(1024, 4) void k_attnE(const __bf16* __restrict__ Qh,
                                                   const __bf16* __restrict__ Ql,
                                                   const __bf16* __restrict__ Kh,
                                                   const __bf16* __restrict__ Vt,
                                                   const float* __restrict__ Rg,
                                                   const int* __restrict__ mask,
                                                   const unsigned char* __restrict__ flags,
                                                   const float* __restrict__ qnorm,
                                                   const float* __restrict__ Rmax,
                                                   const float* __restrict__ Kmax,
                                                   __bf16* __restrict__ E,
                                                   float* __restrict__ attn,
                                                   __bf16* __restrict__ ctx) {
    __shared__ __bf16 sK[2][64][76], sV[2][64][76], sP[128][76];
    __shared__ float sLsum[2][128];
    __shared__ float sLi[128];
    const int flat = blockIdx.x;
    const int swz = (flat & 7) * 64 + (flat >> 3); // XCD-chunked bijection (512 = 8*64)
    const int qt = swz & 15, bh = swz >> 4;
    const int b = bh >> 4, h = bh & 15;
    const int q0 = qt * 128;
    const int tid = threadIdx.x, lane = tid & 63, w = tid >> 6; // w: 0..15
    const int wr = w >> 1, wc = w & 1;
    const int fr = lane & 15, fq = (lane >> 4) & 3, fo = fq * 8;
    const int myrow = wr * 16 + fq * 4;

    // Q fragments for this wave's 16 rows (same for both wc halves)
    const size_t qbase = (size_t)(b * S_ + q0 + wr * 16 + fr) * D_ + h * HD_;
    v8bf qa_h[2], qa_l[2];
#pragma unroll
    for (int ks = 0; ks < 2; ks++) {
        qa_h[ks] = *(const v8bf*)(Qh + qbase + ks * 32 + fo);
        qa_l[ks] = *(const v8bf*)(Ql + qbase + ks * 32 + fo);
    }

    const int qg0 = q0 + myrow;
    const size_t rbase0 = ((size_t)bh * S_ + qg0) * RSTRIDE_;
    const size_t mbase0 = ((size_t)b * S_ + qg0) * S_;
    float rcL[4], rcR[4], mhat[4];
    int flr[4];
    const float km = Kmax[bh] * 0.125f;
#pragma unroll
    for (int r = 0; r < 4; r++) {
        rcL[r] = Rg[rbase0 + (size_t)r * RSTRIDE_];
        rcR[r] = Rg[rbase0 + (size_t)r * RSTRIDE_ + 256];
        flr[r] = flags[(size_t)b * S_ + qg0 + r];
        mhat[r] = Rmax[(size_t)bh * S_ + qg0 + r] +
                  qnorm[(size_t)bh * S_ + qg0 + r] * km + 0.5f;
    }

    // E copy: 16 waves x 8 rows; lane covers 16B: full 128B line per 8 lanes
    const int erow = w * 8 + (lane >> 3);
    const int ec = (lane & 7) * 8;
    __bf16* ebase = E + ((size_t)bh * S_ + q0 + erow) * S_ + ec;

    // staging role: waves 0-7 stage K, waves 8-15 stage V
    const int st = (w < 8) ? tid : tid - 512;
    const int srow = st >> 3, sc8 = (st & 7) * 8;
    const __bf16* gptr;
    size_t gstep;
    if (w < 8) {
        gptr = Kh + (size_t)(b * S_ + srow) * D_ + h * HD_ + sc8;
        gstep = (size_t)64 * D_;
    } else {
        gptr = Vt + (size_t)(b * D_ + h * HD_ + srow) * S_ + sc8;
        gstep = 64;
    }
    // prologue: chunk 0 -> buf0; prefetch chunk 1
    {
        v8bf r0 = *(const v8bf*)(gptr);
        if (w < 8) *(v8bf*)&sK[0][srow][sc8] = r0;
        else       *(v8bf*)&sV[0][srow][sc8] = r0;
    }
    v8bf rg = *(const v8bf*)(gptr + gstep);
    __syncthreads();

    float lrun[4] = {0.0f, 0.0f, 0.0f, 0.0f};
    v4f acc2[2] = {};
    int cur = 0;
    for (int kc = 0; kc < 32; kc++) {
        const int k0 = kc * 64;
        // ---- phase A: QK MFMA (this wave's 32 cols) ----
        v4f acc[2] = {};
#pragma unroll
        for (int ct = 0; ct < 2; ct++) {
#pragma unroll
            for (int ks = 0; ks < 2; ks++) {
                v8bf kb = *(const v8bf*)&sK[cur][wc * 32 + ct * 16 + fr][ks * 32 + fo];
                acc[ct] = mfma16(qa_h[ks], kb, acc[ct]);
                acc[ct] = mfma16(qa_l[ks], kb, acc[ct]);
            }
        }
        // ---- phase B: scores + exp + lrun + sP write ----
        const bool band = (kc >= 2 * qt - 3) && (kc <= 2 * qt + 3);
        const bool left = kc < 2 * qt;
#pragma unroll
        for (int r = 0; r < 4; r++) {
            const int qg = qg0 + r;
#pragma unroll
            for (int ct = 0; ct < 2; ct++) {
                const int k = k0 + wc * 32 + ct * 16 + fr;
                float bias;
                if (band) {
                    const int dd = k - qg;
                    const int j = dd < -128 ? 0 : (dd > 128 ? 256 : dd + 128);
                    bias = Rg[rbase0 + (size_t)r * RSTRIDE_ + j];
                } else {
                    bias = left ? rcL[r] : rcR[r];
                }
                float sv = acc[ct][r] * 0.125f + bias;
                if (!flr[r] && mask[mbase0 + (size_t)r * S_ + k] == 0) sv = -1e9f;
                const float e = __expf(sv - mhat[r]);
                lrun[r] += e;
                sP[myrow + r][wc * 32 + ct * 16 + fr] = (__bf16)e;
            }
        }
        // ---- phase C: stage chunk kc+1 (old rg); prefetch kc+2 ----
        if (kc < 31) {
            if (w < 8) *(v8bf*)&sK[cur ^ 1][srow][sc8] = rg;
            else       *(v8bf*)&sV[cur ^ 1][srow][sc8] = rg;
        }
        if (kc < 30) rg = *(const v8bf*)(gptr + (size_t)(kc + 2) * gstep);
        // ---- barrier 1: sP (both halves) + staging visible ----
        __builtin_amdgcn_sched_barrier(0);
        asm volatile("s_waitcnt lgkmcnt(0)" ::: "memory");
        __builtin_amdgcn_s_barrier();
        __builtin_amdgcn_sched_barrier(0);
        // ---- phase D: PV (full-k rows of sP x this wave's 32 d-cols) ----
#pragma unroll
        for (int ks = 0; ks < 2; ks++) {
            v8bf pa = *(const v8bf*)&sP[wr * 16 + fr][ks * 32 + fo];
#pragma unroll
            for (int ct = 0; ct < 2; ct++) {
                v8bf vb = *(const v8bf*)&sV[cur][wc * 32 + ct * 16 + fr][ks * 32 + fo];
                acc2[ct] = mfma16(pa, vb, acc2[ct]);
            }
        }
        // E copy: row-assigned, full 128B line per 8 lanes
        *(v8bf*)(ebase + k0) = *(const v8bf*)&sP[erow][ec];
        // ---- barrier 2: sP/sV reads done before next chunk overwrites ----
        __builtin_amdgcn_sched_barrier(0);
        asm volatile("s_waitcnt lgkmcnt(0)" ::: "memory");
        __builtin_amdgcn_s_barrier();
        __builtin_amdgcn_sched_barrier(0);
        cur ^= 1;
    }

    // l: reduce over fr lanes, then merge across wc halves via LDS
#pragma unroll
    for (int r = 0; r < 4; r++) {
#pragma unroll
        for (int sh = 1; sh < 16; sh <<= 1) lrun[r] += __shfl_xor(lrun[r], sh);
    }
    if (fr == 0) {
#pragma unroll
        for (int r = 0; r < 4; r++) sLsum[wc][myrow + r] = lrun[r];
    }
    __syncthreads();
    float invl[4];
#pragma unroll
    for (int r = 0; r < 4; r++)
        invl[r] = 1.0f / (sLsum[0][myrow + r] + sLsum[1][myrow + r] + 1e-37f);
    if (wc == 0 && fr == 0) {
#pragma unroll
        for (int r = 0; r < 4; r++) sLi[myrow + r] = invl[r];
    }

    // ctx write (normalized): this wave's 16 rows x 32 d-cols
#pragma unroll
    for (int ct = 0; ct < 2; ct++) {
#pragma unroll
        for (int r = 0; r < 4; r++) {
            const int qg = qg0 + r;
            const int d = wc * 32 + ct * 16 + fr;
            ctx[(size_t)(b * S_ + qg) * D_ + h * HD_ + d] = (__bf16)(acc2[ct][r] * invl[r]);
        }
    }

    // Full drain before epilogue (E stores to L2; sLi visible)
    asm volatile("s_waitcnt vmcnt(0)" ::: "memory");
    __syncthreads();

    // Epilogue: rescale own E slice -> attn fp32
    const __bf16* Eblk = E + ((size_t)bh * S_ + q0) * S_;
    float* ablk = attn + ((size_t)bh * S_ + q0) * S_;
#pragma unroll 4
    for (int it = 0; it < 32; it++) {
        const int g = tid + it * 1024;    // 0..32767 (128 rows x 256 groups)
        const int row = g >> 8;
        const int col8 = (g & 255) * 8;
        const float inv = sLi[row];
        const v8bf e = *(const v8bf*)(Eblk + (size_t)row * S_ + col8);
        float4 o0, o1;
        o0.x = (float)e[0] * inv; o0.y = (float)e[1] * inv;
        o0.z = (float)e[2] * inv; o0.w = (float)e[3] * inv;
        o1.x = (float)e[4] * inv; o1.y = (float)e[5] * inv;
        o1.z = (float)e[6] * inv; o1.w = (float)e[7] * inv;
        *(float4*)(ablk + (size_t)row * S_ + col8)     = o0;
        *(float4*)(ablk + (size_t)row * S_ + col8 + 4) = o1;
    }
}

// ---------------------------------------------------------------------------
// Output projection: out = ctx @ wo^T + bias (stride-76 LDS)
// ---------------------------------------------------------------------------
__global__ __launch_bounds__(256) void k_outproj(const __bf16* __restrict__ A,
                                                 const __bf16* __restrict__ Bw,
                                                 const float* __restrict__ bias,
                                                 float* __restrict__ out) {
    __shared__ __bf16 sA[64][76], sB[64][76];
    const int n0 = blockIdx.x * 64;
    const int m0 = blockIdx.y * 64;
    const int tid = threadIdx.x, lane = tid & 63, wid = tid >> 6;
    const int fr = lane & 15, fo = (lane >> 4) * 8;
    const int srow = tid >> 2, scol = (tid & 3) * 16;
    v4f acc[4] = {};
    for (int k0 = 0; k0 < D_; k0 += 64) {
        const size_t ga = (size_t)(m0 + srow) * D_ + k0 + scol;
        const size_t gb = (size_t)(n0 + srow) * D_ + k0 + scol;
        *(v8bf*)&sA[srow][scol]     = *(const v8bf*)(A + ga);
        *(v8bf*)&sA[srow][scol + 8] = *(const v8bf*)(A + ga + 8);
        *(v8bf*)&sB[srow][scol]     = *(const v8bf*)(Bw + gb);
        *(v8bf*)&sB[srow][scol + 8] = *(const v8bf*)(Bw + gb + 8);
        __syncthreads();
#pragma unroll
        for (int ks = 0; ks < 2; ks++) {
            v8bf a = *(const v8bf*)&sA[wid * 16 + fr][ks * 32 + fo];
#pragma unroll
            for (int nt = 0; nt < 4; nt++) {
                v8bf bb = *(const v8bf*)&sB[nt * 16 + fr][ks * 32 + fo];
                acc[nt] = mfma16(a, bb, acc[nt]);
            }
        }
        __syncthreads();
    }
#pragma unroll
    for (int nt = 0; nt < 4; nt++) {
        const float bv = bias[n0 + nt * 16 + fr];
#pragma unroll
        for (int r = 0; r < 4; r++) {
            const int row = m0 + wid * 16 + (lane >> 4) * 4 + r;
            out[(size_t)row * D_ + n0 + nt * 16 + fr] = acc[nt][r] + bv;
        }
    }
}

// ---------------------------------------------------------------------------
extern "C" void kernel_launch(void* const* d_in, const int* in_sizes, int n_in,
                              void* d_out, int out_size, void* d_ws, size_t ws_size,
                              hipStream_t stream) {
    (void)in_sizes; (void)n_in; (void)out_size; (void)ws_size;
    const float* x    = (const float*)d_in[0];
    const int*   mask = (const int*)d_in[1];
    const float* wq   = (const float*)d_in[2];
    const float* wk   = (const float*)d_in[3];
    const float* wv   = (const float*)d_in[4];
    const float* wo   = (const float*)d_in[5];
    const float* wob  = (const float*)d_in[6];
    const float* rel  = (const float*)d_in[7];
    float* out  = (float*)d_out;
    float* attn = out + (size_t)B_ * S_ * D_;

    char* p = (char*)d_ws;
    auto alloc = [&](size_t bytes) -> char* {
        char* r = p;
        p += (bytes + 255) & ~(size_t)255;
        return r;
    };
    const size_t BSD = (size_t)B_ * S_ * D_;
    const size_t DD  = (size_t)D_ * D_;
    const size_t BHS = (size_t)B_ * H_ * S_;
    __bf16* xh   = (__bf16*)alloc(BSD * 2);
    __bf16* xl   = (__bf16*)alloc(BSD * 2);
    __bf16* wqh  = (__bf16*)alloc(DD * 2);
    __bf16* wkh  = (__bf16*)alloc(DD * 2);
    __bf16* wvh  = (__bf16*)alloc(DD * 2);
    __bf16* woh  = (__bf16*)alloc(DD * 2);
    __bf16* relh = (__bf16*)alloc((size_t)NJ_ * HD_ * 2);
    __bf16* rell = (__bf16*)alloc((size_t)NJ_ * HD_ * 2);
    __bf16* Qh   = (__bf16*)alloc(BSD * 2);
    __bf16* Ql   = (__bf16*)alloc(BSD * 2);
    __bf16* Kh   = (__bf16*)alloc(BSD * 2);
    __bf16* Vt   = (__bf16*)alloc(BSD * 2);
    float*  Rg   = (float*)alloc(BHS * RSTRIDE_ * 4);
    float*  qn   = (float*)alloc(BHS * 4);
    float*  Rmax = (float*)alloc(BHS * 4);
    float*  Kmax = (float*)alloc((size_t)B_ * H_ * 4);
    __bf16* E    = (__bf16*)alloc((size_t)B_ * H_ * S_ * S_ * 2); // 268 MB
    __bf16* ctx  = (__bf16*)alloc(BSD * 2);
    unsigned char* flags = (unsigned char*)alloc((size_t)B_ * S_);

    // 1) fused prep (x split + rel split + weight casts)
    k_prep<<<2048, 256, 0, stream>>>(x, rel, wq, wk, wv, wo,
                                     xh, xl, relh, rell, wqh, wkh, wvh, woh);

    // 2) mask row flags
    k_rowflag<<<B_ * S_, 256, 0, stream>>>(mask, flags);

    // 3) fused QKV projection (V written transposed)
    k_projQKV<<<dim3(48, B_ * S_ / 64), 256, 0, stream>>>(xh, xl, wqh, wkh, wvh,
                                                          Qh, Ql, Kh, Vt);

    // 4) rel bias table + qnorm + Rmax
    k_relgemm<<<dim3(S_ / 64, B_ * H_), 256, 0, stream>>>(Qh, Ql, relh, rell, Rg, qn, Rmax);

    // 5) Kmax per (b,h)
    k_knorm<<<B_ * H_, 256, 0, stream>>>(Kh, Kmax);

    // 6) single-pass attention + fused rescale (attn + ctx), 1024-thread blocks
    k_attnE<<<512, 1024, 0, stream>>>(Qh, Ql, Kh, Vt, Rg, mask, flags, qn, Rmax, Kmax,
                                      E, attn, ctx);

    // 7) output projection
    k_outproj<<<dim3(D_ / 64, B_ * S_ / 64), 256, 0, stream>>>(ctx, woh, wob, out);
}

// Round 19
// 539.326 us; speedup vs baseline: 1.0427x; 1.0427x over previous
//
#include <hip/hip_runtime.h>
#include <hip/hip_bf16.h>

// Problem constants
#define B_ 2
#define S_ 2048
#define H_ 16
#define HD_ 64
#define D_ 1024
#define NJ_ 257      // 2*MAX_REL+1
#define RSTRIDE_ 264 // padded row stride for R (16B aligned)

typedef __bf16 v8bf __attribute__((ext_vector_type(8)));
typedef __bf16 v4bf __attribute__((ext_vector_type(4)));
typedef float  v4f  __attribute__((ext_vector_type(4)));

static __device__ __forceinline__ v4f mfma16(v8bf a, v8bf b, v4f c) {
    return __builtin_amdgcn_mfma_f32_16x16x32_bf16(a, b, c, 0, 0, 0);
}

// ---------------------------------------------------------------------------
// Fused prep: x -> hi/lo split, rel -> hi/lo split, 4 weights -> bf16 cast,
// plus mask row flags (one row per wave, ballot-reduced).
// ---------------------------------------------------------------------------
__global__ void k_prep(const float* __restrict__ x, const float* __restrict__ rel,
                       const float* __restrict__ wq, const float* __restrict__ wk,
                       const float* __restrict__ wv, const float* __restrict__ wo,
                       const int* __restrict__ mask,
                       __bf16* __restrict__ xh, __bf16* __restrict__ xl,
                       __bf16* __restrict__ relh, __bf16* __restrict__ rell,
                       __bf16* __restrict__ wqh, __bf16* __restrict__ wkh,
                       __bf16* __restrict__ wvh, __bf16* __restrict__ woh,
                       unsigned char* __restrict__ flags) {
    const int NX = 1048576;
    const int NR = 4112;
    const int NW = 262144;
    const int total = NX + NR + 4 * NW;
    int i = blockIdx.x * blockDim.x + threadIdx.x;
    const int stride = gridDim.x * blockDim.x;
    for (; i < total; i += stride) {
        if (i < NX + NR) {
            const bool isx = i < NX;
            const int j = isx ? i : i - NX;
            const float* src = isx ? x : rel;
            __bf16* dh = isx ? xh : relh;
            __bf16* dl = isx ? xl : rell;
            const float4 v = ((const float4*)src)[j];
            float vv[4] = {v.x, v.y, v.z, v.w};
            v4bf hv, lv;
#pragma unroll
            for (int e = 0; e < 4; e++) {
                __bf16 hb = (__bf16)vv[e];
                hv[e] = hb;
                lv[e] = (__bf16)(vv[e] - (float)hb);
            }
            *(v4bf*)(dh + 4 * (size_t)j) = hv;
            *(v4bf*)(dl + 4 * (size_t)j) = lv;
        } else {
            const int j = i - NX - NR;
            const int region = j >> 18, idx = j & (NW - 1);
            const float* src = region == 0 ? wq : region == 1 ? wk : region == 2 ? wv : wo;
            __bf16* dst = region == 0 ? wqh : region == 1 ? wkh : region == 2 ? wvh : woh;
            const float4 v = ((const float4*)src)[idx];
            v4bf o = {(__bf16)v.x, (__bf16)v.y, (__bf16)v.z, (__bf16)v.w};
            *(v4bf*)(dst + 4 * (size_t)idx) = o;
        }
    }
    // mask row flags: one row per wave (64 lanes x 8 int4 = 2048 ints = 1 row)
    const int gwave = (blockIdx.x * blockDim.x + threadIdx.x) >> 6;
    const int nwaves = (gridDim.x * blockDim.x) >> 6;
    const int lane = threadIdx.x & 63;
    for (int row = gwave; row < B_ * S_; row += nwaves) {
        const int4* mp = (const int4*)(mask + (size_t)row * S_);
        int ok = 1;
#pragma unroll
        for (int j = 0; j < 8; j++) {
            const int4 m = mp[lane + j * 64];
            ok &= (m.x != 0) & (m.y != 0) & (m.z != 0) & (m.w != 0);
        }
        const unsigned long long bal = __ballot(ok != 0);
        if (lane == 0) flags[row] = (unsigned char)(bal == ~0ull);
    }
}

// ---------------------------------------------------------------------------
// Fused QKV projection (LDS stride 76). seg 0: Q hi/lo; seg 1: K hi;
// seg 2: V -> written TRANSPOSED directly to Vt (fused vtrans).
// ---------------------------------------------------------------------------
__global__ __launch_bounds__(256) void k_projQKV(const __bf16* __restrict__ xh,
                                                 const __bf16* __restrict__ xl,
                                                 const __bf16* __restrict__ wqh,
                                                 const __bf16* __restrict__ wkh,
                                                 const __bf16* __restrict__ wvh,
                                                 __bf16* __restrict__ Qh,
                                                 __bf16* __restrict__ Ql,
                                                 __bf16* __restrict__ Kh,
                                                 __bf16* __restrict__ Vt) {
    __shared__ __bf16 sXh[64][76], sXl[64][76], sW[64][76];
    const int seg = blockIdx.x >> 4;
    const int n0 = (blockIdx.x & 15) * 64;
    const int m0 = blockIdx.y * 64;
    const __bf16* W = seg == 0 ? wqh : (seg == 1 ? wkh : wvh);
    const int tid = threadIdx.x, lane = tid & 63, wid = tid >> 6;
    const int fr = lane & 15, fo = (lane >> 4) * 8;
    const int srow = tid >> 2, scol = (tid & 3) * 16;
    v4f acc[4] = {};
    for (int k0 = 0; k0 < D_; k0 += 64) {
        const size_t ga = (size_t)(m0 + srow) * D_ + k0 + scol;
        const size_t gb = (size_t)(n0 + srow) * D_ + k0 + scol;
        *(v8bf*)&sXh[srow][scol]     = *(const v8bf*)(xh + ga);
        *(v8bf*)&sXh[srow][scol + 8] = *(const v8bf*)(xh + ga + 8);
        if (seg < 2) {
            *(v8bf*)&sXl[srow][scol]     = *(const v8bf*)(xl + ga);
            *(v8bf*)&sXl[srow][scol + 8] = *(const v8bf*)(xl + ga + 8);
        }
        *(v8bf*)&sW[srow][scol]     = *(const v8bf*)(W + gb);
        *(v8bf*)&sW[srow][scol + 8] = *(const v8bf*)(W + gb + 8);
        __syncthreads();
#pragma unroll
        for (int ks = 0; ks < 2; ks++) {
            v8bf ah = *(const v8bf*)&sXh[wid * 16 + fr][ks * 32 + fo];
            v8bf al;
            if (seg < 2) al = *(const v8bf*)&sXl[wid * 16 + fr][ks * 32 + fo];
#pragma unroll
            for (int nt = 0; nt < 4; nt++) {
                v8bf bb = *(const v8bf*)&sW[nt * 16 + fr][ks * 32 + fo];
                acc[nt] = mfma16(ah, bb, acc[nt]);
                if (seg < 2) acc[nt] = mfma16(al, bb, acc[nt]);
            }
        }
        __syncthreads();
    }
    if (seg == 2) {
#pragma unroll
        for (int nt = 0; nt < 4; nt++)
#pragma unroll
            for (int r = 0; r < 4; r++)
                sXh[wid * 16 + (lane >> 4) * 4 + r][nt * 16 + fr] = (__bf16)acc[nt][r];
        __syncthreads();
        const int c = tid >> 2;
        const int r0 = (tid & 3) * 16;
        v8bf o0, o1;
#pragma unroll
        for (int j = 0; j < 8; j++) {
            o0[j] = sXh[r0 + j][c];
            o1[j] = sXh[r0 + 8 + j][c];
        }
        const int b2 = m0 >> 11;
        const size_t gout = ((size_t)(b2 * D_ + n0 + c)) * S_ + (m0 & 2047) + r0;
        *(v8bf*)(Vt + gout)     = o0;
        *(v8bf*)(Vt + gout + 8) = o1;
    } else {
#pragma unroll
        for (int nt = 0; nt < 4; nt++) {
#pragma unroll
            for (int r = 0; r < 4; r++) {
                const int row = m0 + wid * 16 + (lane >> 4) * 4 + r;
                const int col = n0 + nt * 16 + fr;
                const size_t idx = (size_t)row * D_ + col;
                const float f = acc[nt][r];
                if (seg == 0) {
                    __bf16 hb = (__bf16)f;
                    Qh[idx] = hb;
                    Ql[idx] = (__bf16)(f - (float)hb);
                } else {
                    Kh[idx] = (__bf16)f;
                }
            }
        }
    }
}

// ---------------------------------------------------------------------------
// Rel-bias GEMM + qnorm + Rmax; blockIdx.x==32 handles Kmax for bh=blockIdx.y
// ---------------------------------------------------------------------------
__global__ __launch_bounds__(256) void k_relgemm(const __bf16* __restrict__ Qh,
                                                 const __bf16* __restrict__ Ql,
                                                 const __bf16* __restrict__ relh,
                                                 const __bf16* __restrict__ rell,
                                                 const __bf16* __restrict__ Kh,
                                                 float* __restrict__ Rg,
                                                 float* __restrict__ qnorm,
                                                 float* __restrict__ Rmax,
                                                 float* __restrict__ Kmax) {
    __shared__ float red[4];
    const int bh = blockIdx.y;
    const int b = bh >> 4, h = bh & 15;
    const int tid = threadIdx.x, lane = tid & 63, wid = tid >> 6;

    if (blockIdx.x == 32) {
        // Kmax for this (b,h): max over k of ||Kh[b,k,h*64..]||
        float best = 0.0f;
#pragma unroll
        for (int i = 0; i < 8; i++) {
            const int k = tid + i * 256;
            const __bf16* kr = Kh + (size_t)(b * S_ + k) * D_ + h * HD_;
            float s = 0.0f;
#pragma unroll
            for (int j = 0; j < 8; j++) {
                v8bf v = *(const v8bf*)(kr + j * 8);
#pragma unroll
                for (int e = 0; e < 8; e++) { const float f = (float)v[e]; s += f * f; }
            }
            best = fmaxf(best, s);
        }
#pragma unroll
        for (int sh = 1; sh < 64; sh <<= 1) best = fmaxf(best, __shfl_xor(best, sh));
        if ((tid & 63) == 0) red[tid >> 6] = best;
        __syncthreads();
        if (tid == 0)
            Kmax[bh] = sqrtf(fmaxf(fmaxf(red[0], red[1]), fmaxf(red[2], red[3])));
        return;
    }

    const int q0 = blockIdx.x * 64;
    const int fr = lane & 15, fo = (lane >> 4) * 8;
    const size_t qbase = (size_t)(b * S_ + q0 + wid * 16 + fr) * D_ + h * HD_;
    v8bf qa_h[2], qa_l[2];
#pragma unroll
    for (int ks = 0; ks < 2; ks++) {
        qa_h[ks] = *(const v8bf*)(Qh + qbase + ks * 32 + fo);
        qa_l[ks] = *(const v8bf*)(Ql + qbase + ks * 32 + fo);
    }

    float qs = 0.0f;
#pragma unroll
    for (int ks = 0; ks < 2; ks++)
#pragma unroll
        for (int j = 0; j < 8; j++) {
            const float v = (float)qa_h[ks][j] + (float)qa_l[ks][j];
            qs += v * v;
        }
    qs += __shfl_xor(qs, 16);
    qs += __shfl_xor(qs, 32);
    if ((lane >> 4) == 0) qnorm[(size_t)bh * S_ + q0 + wid * 16 + fr] = sqrtf(qs);

    v4f acc[17] = {};
#pragma unroll
    for (int jt = 0; jt < 17; jt++) {
        int j = jt * 16 + fr;
        if (j > 256) j = 256;
        const size_t rb = (size_t)j * HD_;
#pragma unroll
        for (int ks = 0; ks < 2; ks++) {
            v8bf bh_ = *(const v8bf*)(relh + rb + ks * 32 + fo);
            v8bf bl_ = *(const v8bf*)(rell + rb + ks * 32 + fo);
            acc[jt] = mfma16(qa_h[ks], bh_, acc[jt]);
            acc[jt] = mfma16(qa_h[ks], bl_, acc[jt]);
            acc[jt] = mfma16(qa_l[ks], bh_, acc[jt]);
        }
    }

    float rm[4] = {-3.0e38f, -3.0e38f, -3.0e38f, -3.0e38f};
#pragma unroll
    for (int jt = 0; jt < 17; jt++)
#pragma unroll
        for (int r = 0; r < 4; r++) rm[r] = fmaxf(rm[r], acc[jt][r]);
#pragma unroll
    for (int r = 0; r < 4; r++) {
#pragma unroll
        for (int sh = 1; sh < 16; sh <<= 1) rm[r] = fmaxf(rm[r], __shfl_xor(rm[r], sh));
    }
    if (fr == 0) {
#pragma unroll
        for (int r = 0; r < 4; r++)
            Rmax[(size_t)bh * S_ + q0 + wid * 16 + (lane >> 4) * 4 + r] = rm[r];
    }

    const size_t rowbase = ((size_t)bh * S_ + q0 + wid * 16 + (lane >> 4) * 4) * RSTRIDE_;
#pragma unroll
    for (int jt = 0; jt < 17; jt++) {
        const int j = jt * 16 + fr;
        if (j <= 256) {
#pragma unroll
            for (int r = 0; r < 4; r++)
                Rg[rowbase + (size_t)r * RSTRIDE_ + j] = acc[jt][r];
        }
    }
}

// ---------------------------------------------------------------------------
// Single-pass attention (R17 build, unchanged): 128 q-rows/block, dbuf K/V,
// stride-76 LDS, counted-wait barrier, phase-stagger, tk/tv FIFO ordering,
// setprio, full-128B-line E writes, fused rescale epilogue.
// ---------------------------------------------------------------------------
__global__ __launch_bounds__(512, 4) void k_attnE(const __bf16* __restrict__ Qh,
                                                  const __bf16* __restrict__ Ql,
                                                  const __bf16* __restrict__ Kh,
                                                  const __bf16* __restrict__ Vt,
                                                  const float* __restrict__ Rg,
                                                  const int* __restrict__ mask,
                                                  const unsigned char* __restrict__ flags,
                                                  const float* __restrict__ qnorm,
                                                  const float* __restrict__ Rmax,
                                                  const float* __restrict__ Kmax,
                                                  __bf16* __restrict__ E,
                                                  float* __restrict__ attn,
                                                  __bf16* __restrict__ ctx) {
    __shared__ __bf16 sK[2][64][76], sV[2][64][76], sP[128][76];
    __shared__ float sLi[128];
    const int flat = blockIdx.x;
    const int swz = (flat & 7) * 64 + (flat >> 3); // XCD-chunked bijection (512 = 8*64)
    const int qt = swz & 15, bh = swz >> 4;
    const int b = bh >> 4, h = bh & 15;
    const int q0 = qt * 128;
    const int rot = (flat & 1) << 4;
    const int tid = threadIdx.x, lane = tid & 63, w = tid >> 6;
    const int fr = lane & 15, fq = lane >> 4, fo = fq * 8;
    const int myrow = w * 16 + fq * 4;
    const int srow = tid >> 3, sc8 = (tid & 7) * 8;

    const size_t qbase = (size_t)(b * S_ + q0 + w * 16 + fr) * D_ + h * HD_;
    v8bf qa_h[2], qa_l[2];
#pragma unroll
    for (int ks = 0; ks < 2; ks++) {
        qa_h[ks] = *(const v8bf*)(Qh + qbase + ks * 32 + fo);
        qa_l[ks] = *(const v8bf*)(Ql + qbase + ks * 32 + fo);
    }

    const int qg0 = q0 + myrow;
    const size_t rbase0 = ((size_t)bh * S_ + qg0) * RSTRIDE_;
    const size_t mbase0 = ((size_t)b * S_ + qg0) * S_;
    float rcL[4], rcR[4], mhat[4];
    int flr[4];
    const float km = Kmax[bh] * 0.125f;
#pragma unroll
    for (int r = 0; r < 4; r++) {
        rcL[r] = Rg[rbase0 + (size_t)r * RSTRIDE_];
        rcR[r] = Rg[rbase0 + (size_t)r * RSTRIDE_ + 256];
        flr[r] = flags[(size_t)b * S_ + qg0 + r];
        mhat[r] = Rmax[(size_t)bh * S_ + qg0 + r] +
                  qnorm[(size_t)bh * S_ + qg0 + r] * km + 0.5f;
    }

    const int erow = w * 16 + (lane >> 2);
    const int ecol = (lane & 3) * 16;
    __bf16* ebase = E + ((size_t)bh * S_ + q0 + erow) * S_ + ecol;

    const __bf16* kgbase = Kh + (size_t)(b * S_ + srow) * D_ + h * HD_ + sc8;
    const __bf16* vgbase = Vt + (size_t)(b * D_ + h * HD_ + srow) * S_ + sc8;
    {
        v8bf k0v = *(const v8bf*)(kgbase + (size_t)(rot * 64) * D_);
        v8bf v0v = *(const v8bf*)(vgbase + rot * 64);
        *(v8bf*)&sK[0][srow][sc8] = k0v;
        *(v8bf*)&sV[0][srow][sc8] = v0v;
    }
    v8bf rk = *(const v8bf*)(kgbase + (size_t)(((rot + 1) & 31) * 64) * D_);
    v8bf rv = *(const v8bf*)(vgbase + ((rot + 1) & 31) * 64);
    __syncthreads();

    float lrun[4] = {0.0f, 0.0f, 0.0f, 0.0f};
    v4f acc2[4] = {};
    for (int kc = 0; kc < 32; kc++) {
        const int c = (kc + rot) & 31;
        const int k0 = c * 64;
        const int cur = kc & 1;
        v4f acc[4] = {};
        __builtin_amdgcn_s_setprio(1);
#pragma unroll
        for (int ct = 0; ct < 4; ct++) {
#pragma unroll
            for (int ks = 0; ks < 2; ks++) {
                v8bf kb = *(const v8bf*)&sK[cur][ct * 16 + fr][ks * 32 + fo];
                acc[ct] = mfma16(qa_h[ks], kb, acc[ct]);
                acc[ct] = mfma16(qa_l[ks], kb, acc[ct]);
            }
        }
        __builtin_amdgcn_s_setprio(0);
        const bool band = (c >= 2 * qt - 3) && (c <= 2 * qt + 3);
        const bool left = c < 2 * qt;
#pragma unroll
        for (int r = 0; r < 4; r++) {
            const int qg = qg0 + r;
#pragma unroll
            for (int ct = 0; ct < 4; ct++) {
                const int k = k0 + ct * 16 + fr;
                float bias;
                if (band) {
                    const int dd = k - qg;
                    const int j = dd < -128 ? 0 : (dd > 128 ? 256 : dd + 128);
                    bias = Rg[rbase0 + (size_t)r * RSTRIDE_ + j];
                } else {
                    bias = left ? rcL[r] : rcR[r];
                }
                float sv = acc[ct][r] * 0.125f + bias;
                if (!flr[r] && mask[mbase0 + (size_t)r * S_ + k] == 0) sv = -1e9f;
                const float e = __expf(sv - mhat[r]);
                lrun[r] += e;
                sP[myrow + r][ct * 16 + fr] = (__bf16)e;
            }
        }
        __builtin_amdgcn_s_setprio(1);
#pragma unroll
        for (int ks = 0; ks < 2; ks++) {
            v8bf pa = *(const v8bf*)&sP[w * 16 + fr][ks * 32 + fo];
#pragma unroll
            for (int ct = 0; ct < 4; ct++) {
                v8bf vb = *(const v8bf*)&sV[cur][ct * 16 + fr][ks * 32 + fo];
                acc2[ct] = mfma16(pa, vb, acc2[ct]);
            }
        }
        __builtin_amdgcn_s_setprio(0);
        v8bf tk, tv;
        if (kc < 30) {
            const int c2 = (c + 2) & 31;
            tk = *(const v8bf*)(kgbase + (size_t)(c2 * 64) * D_);
            tv = *(const v8bf*)(vgbase + c2 * 64);
        }
        *(v8bf*)(ebase + k0)     = *(const v8bf*)&sP[erow][ecol];
        *(v8bf*)(ebase + k0 + 8) = *(const v8bf*)&sP[erow][ecol + 8];
        if (kc < 31) {
            *(v8bf*)&sK[cur ^ 1][srow][sc8] = rk;
            *(v8bf*)&sV[cur ^ 1][srow][sc8] = rv;
        }
        if (kc < 30) { rk = tk; rv = tv; }
        __builtin_amdgcn_sched_barrier(0);
        asm volatile("s_waitcnt lgkmcnt(0)" ::: "memory");
        __builtin_amdgcn_s_barrier();
        __builtin_amdgcn_sched_barrier(0);
    }

    float invl[4];
#pragma unroll
    for (int r = 0; r < 4; r++) {
#pragma unroll
        for (int sh = 1; sh < 16; sh <<= 1) lrun[r] += __shfl_xor(lrun[r], sh);
        invl[r] = 1.0f / (lrun[r] + 1e-37f);
    }
    if (fr == 0) {
#pragma unroll
        for (int r = 0; r < 4; r++) sLi[myrow + r] = invl[r];
    }

#pragma unroll
    for (int ct = 0; ct < 4; ct++) {
#pragma unroll
        for (int r = 0; r < 4; r++) {
            const int qg = qg0 + r;
            const int d = ct * 16 + fr;
            ctx[(size_t)(b * S_ + qg) * D_ + h * HD_ + d] = (__bf16)(acc2[ct][r] * invl[r]);
        }
    }

    asm volatile("s_waitcnt vmcnt(0)" ::: "memory");
    __syncthreads();

    const __bf16* Eblk = E + ((size_t)bh * S_ + q0) * S_;
    float* ablk = attn + ((size_t)bh * S_ + q0) * S_;
#pragma unroll 4
    for (int it = 0; it < 64; it++) {
        const int g = tid + it * 512;
        const int row = g >> 8;
        const int col8 = (g & 255) * 8;
        const float inv = sLi[row];
        const v8bf e = *(const v8bf*)(Eblk + (size_t)row * S_ + col8);
        float4 o0, o1;
        o0.x = (float)e[0] * inv; o0.y = (float)e[1] * inv;
        o0.z = (float)e[2] * inv; o0.w = (float)e[3] * inv;
        o1.x = (float)e[4] * inv; o1.y = (float)e[5] * inv;
        o1.z = (float)e[6] * inv; o1.w = (float)e[7] * inv;
        *(float4*)(ablk + (size_t)row * S_ + col8)     = o0;
        *(float4*)(ablk + (size_t)row * S_ + col8 + 4) = o1;
    }
}

// ---------------------------------------------------------------------------
// Output projection: out = ctx @ wo^T + bias (stride-76 LDS)
// ---------------------------------------------------------------------------
__global__ __launch_bounds__(256) void k_outproj(const __bf16* __restrict__ A,
                                                 const __bf16* __restrict__ Bw,
                                                 const float* __restrict__ bias,
                                                 float* __restrict__ out) {
    __shared__ __bf16 sA[64][76], sB[64][76];
    const int n0 = blockIdx.x * 64;
    const int m0 = blockIdx.y * 64;
    const int tid = threadIdx.x, lane = tid & 63, wid = tid >> 6;
    const int fr = lane & 15, fo = (lane >> 4) * 8;
    const int srow = tid >> 2, scol = (tid & 3) * 16;
    v4f acc[4] = {};
    for (int k0 = 0; k0 < D_; k0 += 64) {
        const size_t ga = (size_t)(m0 + srow) * D_ + k0 + scol;
        const size_t gb = (size_t)(n0 + srow) * D_ + k0 + scol;
        *(v8bf*)&sA[srow][scol]     = *(const v8bf*)(A + ga);
        *(v8bf*)&sA[srow][scol + 8] = *(const v8bf*)(A + ga + 8);
        *(v8bf*)&sB[srow][scol]     = *(const v8bf*)(Bw + gb);
        *(v8bf*)&sB[srow][scol + 8] = *(const v8bf*)(Bw + gb + 8);
        __syncthreads();
#pragma unroll
        for (int ks = 0; ks < 2; ks++) {
            v8bf a = *(const v8bf*)&sA[wid * 16 + fr][ks * 32 + fo];
#pragma unroll
            for (int nt = 0; nt < 4; nt++) {
                v8bf bb = *(const v8bf*)&sB[nt * 16 + fr][ks * 32 + fo];
                acc[nt] = mfma16(a, bb, acc[nt]);
            }
        }
        __syncthreads();
    }
#pragma unroll
    for (int nt = 0; nt < 4; nt++) {
        const float bv = bias[n0 + nt * 16 + fr];
#pragma unroll
        for (int r = 0; r < 4; r++) {
            const int row = m0 + wid * 16 + (lane >> 4) * 4 + r;
            out[(size_t)row * D_ + n0 + nt * 16 + fr] = acc[nt][r] + bv;
        }
    }
}

// ---------------------------------------------------------------------------
extern "C" void kernel_launch(void* const* d_in, const int* in_sizes, int n_in,
                              void* d_out, int out_size, void* d_ws, size_t ws_size,
                              hipStream_t stream) {
    (void)in_sizes; (void)n_in; (void)out_size; (void)ws_size;
    const float* x    = (const float*)d_in[0];
    const int*   mask = (const int*)d_in[1];
    const float* wq   = (const float*)d_in[2];
    const float* wk   = (const float*)d_in[3];
    const float* wv   = (const float*)d_in[4];
    const float* wo   = (const float*)d_in[5];
    const float* wob  = (const float*)d_in[6];
    const float* rel  = (const float*)d_in[7];
    float* out  = (float*)d_out;
    float* attn = out + (size_t)B_ * S_ * D_;

    char* p = (char*)d_ws;
    auto alloc = [&](size_t bytes) -> char* {
        char* r = p;
        p += (bytes + 255) & ~(size_t)255;
        return r;
    };
    const size_t BSD = (size_t)B_ * S_ * D_;
    const size_t DD  = (size_t)D_ * D_;
    const size_t BHS = (size_t)B_ * H_ * S_;
    __bf16* xh   = (__bf16*)alloc(BSD * 2);
    __bf16* xl   = (__bf16*)alloc(BSD * 2);
    __bf16* wqh  = (__bf16*)alloc(DD * 2);
    __bf16* wkh  = (__bf16*)alloc(DD * 2);
    __bf16* wvh  = (__bf16*)alloc(DD * 2);
    __bf16* woh  = (__bf16*)alloc(DD * 2);
    __bf16* relh = (__bf16*)alloc((size_t)NJ_ * HD_ * 2);
    __bf16* rell = (__bf16*)alloc((size_t)NJ_ * HD_ * 2);
    __bf16* Qh   = (__bf16*)alloc(BSD * 2);
    __bf16* Ql   = (__bf16*)alloc(BSD * 2);
    __bf16* Kh   = (__bf16*)alloc(BSD * 2);
    __bf16* Vt   = (__bf16*)alloc(BSD * 2);
    float*  Rg   = (float*)alloc(BHS * RSTRIDE_ * 4);
    float*  qn   = (float*)alloc(BHS * 4);
    float*  Rmax = (float*)alloc(BHS * 4);
    float*  Kmax = (float*)alloc((size_t)B_ * H_ * 4);
    __bf16* E    = (__bf16*)alloc((size_t)B_ * H_ * S_ * S_ * 2); // 268 MB
    __bf16* ctx  = (__bf16*)alloc(BSD * 2);
    unsigned char* flags = (unsigned char*)alloc((size_t)B_ * S_);

    // 1) fused prep (x/rel splits + weight casts + mask row flags)
    k_prep<<<2048, 256, 0, stream>>>(x, rel, wq, wk, wv, wo, mask,
                                     xh, xl, relh, rell, wqh, wkh, wvh, woh, flags);

    // 2) fused QKV projection (V written transposed)
    k_projQKV<<<dim3(48, B_ * S_ / 64), 256, 0, stream>>>(xh, xl, wqh, wkh, wvh,
                                                          Qh, Ql, Kh, Vt);

    // 3) rel bias table + qnorm + Rmax (+ Kmax in 33rd column)
    k_relgemm<<<dim3(33, B_ * H_), 256, 0, stream>>>(Qh, Ql, relh, rell, Kh,
                                                     Rg, qn, Rmax, Kmax);

    // 4) single-pass attention + fused rescale (attn + ctx)
    k_attnE<<<512, 512, 0, stream>>>(Qh, Ql, Kh, Vt, Rg, mask, flags, qn, Rmax, Kmax,
                                     E, attn, ctx);

    // 5) output projection
    k_outproj<<<dim3(D_ / 64, B_ * S_ / 64), 256, 0, stream>>>(ctx, woh, wob, out);
}